// Round 8
// baseline (282.686 us; speedup 1.0000x reference)
//
#include <hip/hip_runtime.h>
#include <hip/hip_bf16.h>

typedef short short8 __attribute__((ext_vector_type(8)));
typedef __bf16 bf16x8 __attribute__((ext_vector_type(8)));
typedef float f32x4 __attribute__((ext_vector_type(4)));
typedef float f32x8 __attribute__((ext_vector_type(8)));
typedef float f32x16 __attribute__((ext_vector_type(16)));
typedef unsigned int uint4v __attribute__((ext_vector_type(4)));

#define SEQ_N 4096
#define NKEYS 5120
#define PEG_L 5119
#define NSPLIT 2
#define KEYS_PER_SPLIT 2560
#define NT_SPLIT 40

__device__ __forceinline__ float b2f(unsigned short s){
  union{unsigned u; float f;} v; v.u = ((unsigned)s)<<16; return v.f;
}
__device__ __forceinline__ unsigned short f2b(float f){
  unsigned u = __builtin_bit_cast(unsigned, f);
  u += 0x7fffu + ((u>>16)&1u);
  return (unsigned short)(u>>16);
}
__device__ __forceinline__ unsigned cvtpk(float lo, float hi){
  unsigned r;
  asm("v_cvt_pk_bf16_f32 %0, %1, %2" : "=v"(r) : "v"(lo), "v"(hi));
  return r;
}

// ---------------- weight transpose f32 -> bf16 ----------------
__global__ void k_transpose_w(const float* __restrict__ src, unsigned short* __restrict__ dst,
                              int K, int Ncols){
  __shared__ float t[32][33];
  int tx = threadIdx.x, ty = threadIdx.y;
  int bx = blockIdx.x, by = blockIdx.y;
  #pragma unroll
  for (int i=0;i<4;i++){
    int r = by*32 + ty + 8*i, c = bx*32 + tx;
    t[ty+8*i][tx] = src[(size_t)r*Ncols + c];
  }
  __syncthreads();
  #pragma unroll
  for (int i=0;i<4;i++){
    int r = bx*32 + ty + 8*i, c = by*32 + tx;
    dst[(size_t)r*K + c] = f2b(t[tx][ty+8*i]);
  }
}

// ---------------- LayerNorm: x f32 [8192][512] -> xn bf16 ----------------
__global__ __launch_bounds__(256) void k_layernorm(const float* __restrict__ x,
    const float* __restrict__ g, const float* __restrict__ bb,
    unsigned short* __restrict__ xn){
  int w = threadIdx.x >> 6, l = threadIdx.x & 63;
  int row = blockIdx.x*4 + w;
  const float* xr = x + (size_t)row*512 + l*8;
  f32x4 a = *(const f32x4*)xr;
  f32x4 c4 = *(const f32x4*)(xr+4);
  float s = a[0]+a[1]+a[2]+a[3]+c4[0]+c4[1]+c4[2]+c4[3];
  #pragma unroll
  for (int d=1; d<64; d<<=1) s += __shfl_xor(s, d);
  float mu = s * (1.0f/512.0f);
  float vs = 0.f;
  #pragma unroll
  for (int i=0;i<4;i++){ float d0=a[i]-mu; vs += d0*d0; }
  #pragma unroll
  for (int i=0;i<4;i++){ float d0=c4[i]-mu; vs += d0*d0; }
  #pragma unroll
  for (int d=1; d<64; d<<=1) vs += __shfl_xor(vs, d);
  float rstd = rsqrtf(vs*(1.0f/512.0f) + 1e-5f);
  const float* gp = g + l*8;
  const float* bp = bb + l*8;
  unsigned short o[8];
  #pragma unroll
  for (int i=0;i<8;i++){
    float xi = (i<4)? a[i] : c4[i-4];
    o[i] = f2b((xi-mu)*rstd*gp[i] + bp[i]);
  }
  *(short8*)(xn + (size_t)row*512 + l*8) = *(short8*)o;
}

// ---------------- mem f32 -> bf16 into kf/vf rows 4096..5119 ----------------
__global__ void k_memcat(const float* __restrict__ mem,
                         unsigned short* __restrict__ kf, unsigned short* __restrict__ vf){
  size_t e0 = ((size_t)blockIdx.x*256 + threadIdx.x)*8;
  f32x4 a = *(const f32x4*)(mem+e0);
  f32x4 c4 = *(const f32x4*)(mem+e0+4);
  unsigned short o[8];
  #pragma unroll
  for (int i=0;i<8;i++) o[i] = f2b((i<4)? a[i] : c4[i-4]);
  int c = (int)(e0 & 511);
  size_t row = e0 >> 9;
  size_t b = row >> 10, r = row & 1023;
  size_t dst = ((b*NKEYS) + 4096 + r)*512 + c;
  *(short8*)(kf+dst) = *(short8*)o;
  *(short8*)(vf+dst) = *(short8*)o;
}

// ---------------- GEMM 128x128 tile, BK=64 ----------------
// EPI 0: A = xn, QKV routing epilogue.
// EPI 1: A = combine(oP splits) staged on the fly (kt == head), out f32 + bias.
template<int EPI>
__global__ __launch_bounds__(256) void k_gemm2(const unsigned short* __restrict__ A,
    const unsigned short* __restrict__ BT, const float* __restrict__ bias,
    unsigned short* __restrict__ qb, unsigned short* __restrict__ kf,
    unsigned short* __restrict__ vf, float* __restrict__ outf,
    const unsigned short* __restrict__ oPp, const float* __restrict__ comb){
  __shared__ unsigned short Al[128][72];
  __shared__ unsigned short Bl[128][72];
  const int tid = threadIdx.x;
  const int w = tid>>6, l = tid&63, m = l&15, hh = l>>4;
  const int m0 = blockIdx.x*128, n0 = blockIdx.y*128;
  f32x4 acc[2][8];
  #pragma unroll
  for (int mt=0; mt<2; ++mt)
    #pragma unroll
    for (int nt=0; nt<8; ++nt) acc[mt][nt] = f32x4{0.f,0.f,0.f,0.f};

  for (int kt=0; kt<8; ++kt){
    short8 av[4], bv[4];
    #pragma unroll
    for (int i=0;i<4;++i){
      int c = tid + i*256;          // 0..1023
      int row = c >> 3, c8 = (c & 7)*8;
      if (EPI==0){
        av[i] = *(const short8*)(A + (size_t)(m0+row)*512 + kt*64 + c8);
      } else {
        int gr = m0 + row;
        int b2 = gr >> 12, q = gr & 4095;
        size_t ibase = ((size_t)(b2*8 + kt)*SEQ_N + q)*64 + c8;
        short8 x0 = *(const short8*)(oPp + ibase);
        short8 x1 = *(const short8*)(oPp + (size_t)16*SEQ_N*64 + ibase);
        size_t ci = ((size_t)(b2*8 + kt)*SEQ_N + q)*2;
        float a0 = comb[ci], a1 = comb[ci+1];
        unsigned short t8[8];
        #pragma unroll
        for (int j=0;j<8;++j)
          t8[j] = f2b(a0*b2f((unsigned short)x0[j]) + a1*b2f((unsigned short)x1[j]));
        av[i] = *(short8*)t8;
      }
      bv[i] = *(const short8*)(BT + (size_t)(n0+row)*512 + kt*64 + c8);
    }
    __syncthreads();
    #pragma unroll
    for (int i=0;i<4;++i){
      int c = tid + i*256;
      int row = c >> 3, c8 = (c & 7)*8;
      *(short8*)&Al[row][c8] = av[i];
      *(short8*)&Bl[row][c8] = bv[i];
    }
    __syncthreads();
    #pragma unroll
    for (int ks=0; ks<2; ++ks){
      bf16x8 af[2];
      #pragma unroll
      for (int mt=0; mt<2; ++mt)
        af[mt] = *(const bf16x8*)&Al[w*32 + mt*16 + m][ks*32 + hh*8];
      #pragma unroll
      for (int nt=0; nt<8; ++nt){
        bf16x8 bfv = *(const bf16x8*)&Bl[nt*16+m][ks*32 + hh*8];
        #pragma unroll
        for (int mt=0; mt<2; ++mt)
          acc[mt][nt] = __builtin_amdgcn_mfma_f32_16x16x32_bf16(af[mt], bfv, acc[mt][nt], 0,0,0);
      }
    }
  }
  #pragma unroll
  for (int mt=0; mt<2; ++mt){
    #pragma unroll
    for (int nt=0; nt<8; ++nt){
      #pragma unroll
      for (int j=0; j<4; ++j){
        int grow = m0 + w*32 + mt*16 + 4*hh + j;
        int gcol = n0 + nt*16 + m;
        float v = acc[mt][nt][j];
        if (EPI==0){
          int b = grow >> 12, n = grow & 4095;
          if (gcol < 512)       qb[(size_t)grow*512 + gcol] = f2b(v);
          else if (gcol < 1024) kf[((size_t)b*NKEYS + n)*512 + (gcol-512)]  = f2b(v);
          else                  vf[((size_t)b*NKEYS + n)*512 + (gcol-1024)] = f2b(v);
        } else {
          outf[(size_t)grow*512 + gcol] = v + bias[gcol];
        }
      }
    }
  }
}

// ---------------- PEG1D on rows 1..5119; blockIdx.y selects K(0)/V(1) ----------------
__global__ __launch_bounds__(256) void k_peg(const unsigned short* __restrict__ ink,
    const unsigned short* __restrict__ inv,
    const float* __restrict__ w3k, const float* __restrict__ w3v,
    const float* __restrict__ bk, const float* __restrict__ bvp,
    unsigned short* __restrict__ outk, unsigned short* __restrict__ outv){
  const int kv = blockIdx.y;
  const unsigned short* in = kv ? inv : ink;
  const float* w3 = kv ? w3v : w3k;
  const float* bias = kv ? bvp : bk;
  unsigned short* out = kv ? outv : outk;
  int idx = blockIdx.x*256 + threadIdx.x;
  int cg = idx & 63;
  int i  = (idx >> 6) % NKEYS;
  int b  = (idx >> 6) / NKEYS;
  int c0 = cg*8;
  const unsigned short* base = in + (size_t)b*NKEYS*512 + c0;
  unsigned short* op = out + ((size_t)b*NKEYS + i)*512 + c0;
  if (i == 0){ *(short8*)op = *(const short8*)base; return; }
  int j = i - 1;
  float wv0[8], wv1[8], wv2[8], bv[8], acc[8];
  #pragma unroll
  for (int k2=0;k2<8;k2++){
    wv0[k2] = w3[(c0+k2)*3 + 0];
    wv1[k2] = w3[(c0+k2)*3 + 1];
    wv2[k2] = w3[(c0+k2)*3 + 2];
    bv[k2]  = bias[c0+k2];
  }
  short8 xc = *(const short8*)(base + (size_t)i*512);
  #pragma unroll
  for (int k2=0;k2<8;k2++)
    acc[k2] = b2f((unsigned short)xc[k2]) * (1.0f + 2.0f*wv1[k2]) + 2.0f*bv[k2];
  int r = j & 31;
  int jj = j + 16; if (jj >= PEG_L) jj -= PEG_L;
  int r2 = jj & 31;
  if (r > 0){
    short8 xl = *(const short8*)(base + (size_t)j*512);
    #pragma unroll
    for (int k2=0;k2<8;k2++) acc[k2] += wv0[k2]*b2f((unsigned short)xl[k2]);
  }
  if (r < 31 && j+1 < PEG_L){
    short8 xr = *(const short8*)(base + (size_t)(j+2)*512);
    #pragma unroll
    for (int k2=0;k2<8;k2++) acc[k2] += wv2[k2]*b2f((unsigned short)xr[k2]);
  }
  if (r2 > 0){
    int p = jj - 17; if (p < 0) p += PEG_L;
    short8 xl = *(const short8*)(base + (size_t)(p+1)*512);
    #pragma unroll
    for (int k2=0;k2<8;k2++) acc[k2] += wv0[k2]*b2f((unsigned short)xl[k2]);
  }
  if (r2 < 31 && jj+1 < PEG_L){
    int p = jj - 15; if (p < 0) p += PEG_L;
    short8 xr = *(const short8*)(base + (size_t)(p+1)*512);
    #pragma unroll
    for (int k2=0;k2<8;k2++) acc[k2] += wv2[k2]*b2f((unsigned short)xr[k2]);
  }
  unsigned short o[8];
  #pragma unroll
  for (int k2=0;k2<8;k2++) o[k2] = f2b(acc[k2]);
  *(short8*)op = *(short8*)o;
}

// ---------------- V transpose: vp [B][5120][512] -> vpT [B*H][64][5120] ----------------
__global__ __launch_bounds__(256) void k_vtrans(const unsigned short* __restrict__ vp,
                                                unsigned short* __restrict__ vpT){
  __shared__ unsigned short t[64][72];
  const int bh = blockIdx.y, b = bh>>3, h = bh&7;
  const int k0 = blockIdx.x*64;
  const int tid = threadIdx.x;
  #pragma unroll
  for (int it=0; it<2; ++it){
    int idx = tid + it*256;
    int key = idx>>3, dg = idx&7;
    short8 v = *(const short8*)(vp + ((size_t)b*NKEYS + k0+key)*512 + h*64 + dg*8);
    #pragma unroll
    for (int jj=0;jj<8;++jj) t[dg*8+jj][key] = (unsigned short)v[jj];
  }
  __syncthreads();
  #pragma unroll
  for (int it=0; it<2; ++it){
    int idx = tid + it*256;
    int d = idx>>3, kg = idx&7;
    short8 v = *(const short8*)&t[d][kg*8];
    *(short8*)(vpT + ((size_t)bh*64 + d)*NKEYS + k0 + kg*8) = v;
  }
}

// ---------------- Flash attention (key-split): swapped QK^T, 32x32, in-reg softmax ----------------
// launch_bounds(256,3): 170 reg/wave budget so s0/s1+temps stay in arch VGPRs (no AGPR shuttle).
__global__ __launch_bounds__(256, 3) void k_attn(
    const unsigned short* __restrict__ qb,
    const unsigned short* __restrict__ kp,
    const unsigned short* __restrict__ vpT,
    unsigned short* __restrict__ oP,
    float* __restrict__ ml){
  __shared__ unsigned short Kl[2][64][72];
  __shared__ unsigned short Vl[2][64][72];
  const int tid = threadIdx.x;
  const int w = tid >> 6, lid = tid & 63;
  const int lq = lid & 31, hi = lid >> 5;
  const int bh = blockIdx.y, b = bh >> 3, h = bh & 7;
  const int sp = blockIdx.z;
  const int q = blockIdx.x*128 + w*32 + lq;

  bf16x8 qreg[4];
  {
    const unsigned short* qr = qb + (size_t)(b*SEQ_N + q)*512 + h*64 + hi*8;
    #pragma unroll
    for (int dt=0; dt<4; ++dt) qreg[dt] = *(const bf16x8*)(qr + dt*16);
  }

  f32x16 o0 = {}, o1 = {};
  f32x8 lsum8 = {};
  float mraw = -3.0e38f;

  const int srow = tid >> 2, sg = tid & 3;
  const unsigned short* kst = kp + (size_t)b*NKEYS*512 + h*64
                              + (size_t)(sp*KEYS_PER_SPLIT)*512 + (size_t)srow*512 + sg*8;
  const unsigned short* vst = vpT + (size_t)bh*64*NKEYS + (size_t)srow*NKEYS
                              + sp*KEYS_PER_SPLIT + sg*8;

  {
    short8 a0 = *(const short8*)(kst);
    short8 a1 = *(const short8*)(kst + 32);
    short8 v0 = *(const short8*)(vst);
    short8 v1 = *(const short8*)(vst + 32);
    *(short8*)&Kl[0][srow][sg*8]    = a0;
    *(short8*)&Kl[0][srow][32+sg*8] = a1;
    *(short8*)&Vl[0][srow][sg*8]    = v0;
    *(short8*)&Vl[0][srow][32+sg*8] = v1;
  }
  __syncthreads();

  const float c2 = 0.18033688011f;   // 0.125 * log2(e)
  int cur = 0;
  for (int kt=0; kt<NT_SPLIT; ++kt){
    short8 a0, a1, v0s, v1s;
    const bool pf = (kt+1) < NT_SPLIT;
    if (pf){
      const unsigned short* kn = kst + (size_t)(kt+1)*64*512;
      const unsigned short* vn = vst + (size_t)(kt+1)*64;
      a0  = *(const short8*)(kn);
      a1  = *(const short8*)(kn + 32);
      v0s = *(const short8*)(vn);
      v1s = *(const short8*)(vn + 32);
    }

    f32x16 s0 = {}, s1 = {};
    #pragma unroll
    for (int dt=0; dt<4; ++dt){
      bf16x8 kf0 = *(const bf16x8*)&Kl[cur][lq][dt*16 + hi*8];
      s0 = __builtin_amdgcn_mfma_f32_32x32x16_bf16(kf0, qreg[dt], s0, 0,0,0);
    }
    #pragma unroll
    for (int dt=0; dt<4; ++dt){
      bf16x8 kf1 = *(const bf16x8*)&Kl[cur][32+lq][dt*16 + hi*8];
      s1 = __builtin_amdgcn_mfma_f32_32x32x16_bf16(kf1, qreg[dt], s1, 0,0,0);
    }

    // local (this half's) max via packed tree
    f32x8 sa0 = __builtin_shufflevector(s0, s0, 0,1,2,3,4,5,6,7);
    f32x8 sb0 = __builtin_shufflevector(s0, s0, 8,9,10,11,12,13,14,15);
    f32x8 sa1 = __builtin_shufflevector(s1, s1, 0,1,2,3,4,5,6,7);
    f32x8 sb1 = __builtin_shufflevector(s1, s1, 8,9,10,11,12,13,14,15);
    f32x8 mx8 = __builtin_elementwise_max(__builtin_elementwise_max(sa0, sb0),
                                          __builtin_elementwise_max(sa1, sb1));
    float pm = fmaxf(fmaxf(fmaxf(mx8[0],mx8[1]), fmaxf(mx8[2],mx8[3])),
                     fmaxf(fmaxf(mx8[4],mx8[5]), fmaxf(mx8[6],mx8[7])));

    // defer-max: cross-half exchange + rescale only when some lane exceeds slack
    if (!__all(pm <= mraw + 64.0f)){
      float pg = fmaxf(pm, __shfl_xor(pm, 32, 64));
      float mnew = fmaxf(mraw, pg);
      float al = __builtin_amdgcn_exp2f((mraw - mnew)*c2);
      #pragma unroll
      for (int i=0;i<16;++i){ o0[i]*=al; o1[i]*=al; }
      #pragma unroll
      for (int i=0;i<8;++i) lsum8[i] *= al;
      mraw = mnew;
    }
    const float nmc = -(mraw * c2);
    #pragma unroll
    for (int i=0;i<16;++i){
      s0[i] = __builtin_amdgcn_exp2f(fmaf(s0[i], c2, nmc));
      s1[i] = __builtin_amdgcn_exp2f(fmaf(s1[i], c2, nmc));
    }
    // vector partial sum (horizontal reduce deferred to epilogue)
    {
      f32x8 pa0 = __builtin_shufflevector(s0, s0, 0,1,2,3,4,5,6,7);
      f32x8 pb0 = __builtin_shufflevector(s0, s0, 8,9,10,11,12,13,14,15);
      f32x8 pa1 = __builtin_shufflevector(s1, s1, 0,1,2,3,4,5,6,7);
      f32x8 pb1 = __builtin_shufflevector(s1, s1, 8,9,10,11,12,13,14,15);
      lsum8 += (pa0 + pb0) + (pa1 + pb1);
    }

    // P -> bf16 B-fragments (HW cvt_pk), one cross-half exchange per 16-key slice
    #pragma unroll
    for (int sl=0; sl<4; ++sl){
      const f32x16& sv = (sl < 2) ? s0 : s1;
      const int rb = (sl & 1)*8;
      unsigned w0 = cvtpk(sv[rb+0], sv[rb+1]);
      unsigned w1 = cvtpk(sv[rb+2], sv[rb+3]);
      unsigned w2 = cvtpk(sv[rb+4], sv[rb+5]);
      unsigned w3 = cvtpk(sv[rb+6], sv[rb+7]);
      unsigned u0 = hi ? w0 : w2;
      unsigned u1 = hi ? w1 : w3;
      unsigned su0 = __shfl_xor(u0, 32, 64);
      unsigned su1 = __shfl_xor(u1, 32, 64);
      unsigned e0 = hi ? su0 : w0;
      unsigned e1 = hi ? su1 : w1;
      unsigned e2 = hi ? w2 : su0;
      unsigned e3 = hi ? w3 : su1;
      uint4v wv = {e0, e1, e2, e3};
      bf16x8 pb = __builtin_bit_cast(bf16x8, wv);
      bf16x8 vf0 = *(const bf16x8*)&Vl[cur][lq][sl*16 + hi*8];
      o0 = __builtin_amdgcn_mfma_f32_32x32x16_bf16(vf0, pb, o0, 0,0,0);
      bf16x8 vf1 = *(const bf16x8*)&Vl[cur][32+lq][sl*16 + hi*8];
      o1 = __builtin_amdgcn_mfma_f32_32x32x16_bf16(vf1, pb, o1, 0,0,0);
    }

    if (pf){
      *(short8*)&Kl[cur^1][srow][sg*8]    = a0;
      *(short8*)&Kl[cur^1][srow][32+sg*8] = a1;
      *(short8*)&Vl[cur^1][srow][sg*8]    = v0s;
      *(short8*)&Vl[cur^1][srow][32+sg*8] = v1s;
    }
    __syncthreads();
    cur ^= 1;
  }

  f32x4 l4 = f32x4{lsum8[0],lsum8[1],lsum8[2],lsum8[3]} + f32x4{lsum8[4],lsum8[5],lsum8[6],lsum8[7]};
  float lsum = (l4[0]+l4[1]) + (l4[2]+l4[3]);
  const float lt = lsum + __shfl_xor(lsum, 32, 64);
  const float inv = __builtin_amdgcn_rcpf(lt);
  unsigned short* op = oP + (((size_t)(sp*16 + bh)*SEQ_N + q)*64);
  #pragma unroll
  for (int r=0; r<16; r+=2){
    const int dloc = (r&3) + 8*(r>>2) + 4*hi;
    *(unsigned*)(op + dloc)      = cvtpk(o0[r]*inv, o0[r+1]*inv);
    *(unsigned*)(op + 32 + dloc) = cvtpk(o1[r]*inv, o1[r+1]*inv);
  }
  float* mlp = ml + ((size_t)(sp*16 + bh)*SEQ_N + q)*2;
  mlp[0] = mraw;
  mlp[1] = lt;
}

// ---------------- per-(bh,q) combine weights for the fused out-GEMM ----------------
__global__ __launch_bounds__(256) void k_mlw(const float* __restrict__ ml,
                                             float* __restrict__ comb){
  const float c2 = 0.18033688011f;
  int idx = blockIdx.x*256 + threadIdx.x;     // 16*4096
  size_t i0 = idx;
  size_t i1 = (size_t)16*SEQ_N + idx;
  float m0 = ml[i0*2], l0 = ml[i0*2+1];
  float m1 = ml[i1*2], l1 = ml[i1*2+1];
  float ms = fmaxf(m0, m1);
  float w0 = l0 * __builtin_amdgcn_exp2f((m0 - ms)*c2);
  float w1 = l1 * __builtin_amdgcn_exp2f((m1 - ms)*c2);
  float inv = 1.0f / (w0 + w1);
  comb[(size_t)idx*2]   = w0*inv;
  comb[(size_t)idx*2+1] = w1*inv;
}

extern "C" void kernel_launch(void* const* d_in, const int* in_sizes, int n_in,
                              void* d_out, int out_size, void* d_ws, size_t ws_size,
                              hipStream_t stream){
  const float* x     = (const float*)d_in[0];
  const float* mem   = (const float*)d_in[1];
  const float* ln_g  = (const float*)d_in[2];
  const float* ln_b  = (const float*)d_in[3];
  const float* w_qkv = (const float*)d_in[4];
  const float* w_out = (const float*)d_in[5];
  const float* b_out = (const float*)d_in[6];
  const float* pk_w  = (const float*)d_in[7];
  const float* pk_b  = (const float*)d_in[8];
  const float* pv_w  = (const float*)d_in[9];
  const float* pv_b  = (const float*)d_in[10];
  float* outp = (float*)d_out;

  char* ws = (char*)d_ws;
  size_t off = 0;
  auto alloc = [&](size_t bytes)->void*{
    void* p = ws + off; off += (bytes + 255) & ~(size_t)255; return p;
  };
  unsigned short* wqkvT = (unsigned short*)alloc((size_t)1536*512*2);
  unsigned short* woutT = (unsigned short*)alloc((size_t)512*512*2);
  unsigned short* xn    = (unsigned short*)alloc((size_t)8192*512*2);
  unsigned short* q_b   = (unsigned short*)alloc((size_t)8192*512*2);
  unsigned short* kf    = (unsigned short*)alloc((size_t)2*NKEYS*512*2);
  unsigned short* vf    = (unsigned short*)alloc((size_t)2*NKEYS*512*2);
  unsigned short* kpg   = (unsigned short*)alloc((size_t)2*NKEYS*512*2);
  unsigned short* vpg   = (unsigned short*)alloc((size_t)2*NKEYS*512*2);
  unsigned short* vpT   = (unsigned short*)alloc((size_t)2*NKEYS*512*2);
  unsigned short* attnb = (unsigned short*)alloc((size_t)8192*512*2);

  // Split-attention partials overlay dead kf/vf; comb overlays dead attnb.
  unsigned short* oP = kf;
  float* ml = (float*)((char*)kf + (size_t)NSPLIT*16*SEQ_N*64*2);
  float* comb = (float*)attnb;

  k_transpose_w<<<dim3(48,16), dim3(32,8), 0, stream>>>(w_qkv, wqkvT, 512, 1536);
  k_transpose_w<<<dim3(16,16), dim3(32,8), 0, stream>>>(w_out, woutT, 512, 512);
  k_layernorm<<<2048, 256, 0, stream>>>(x, ln_g, ln_b, xn);
  k_memcat<<<512, 256, 0, stream>>>(mem, kf, vf);
  k_gemm2<0><<<dim3(64,12), 256, 0, stream>>>(xn, wqkvT, nullptr, q_b, kf, vf, nullptr, nullptr, nullptr);
  k_peg<<<dim3(2560,2), 256, 0, stream>>>(kf, vf, pk_w, pv_w, pk_b, pv_b, kpg, vpg);
  k_vtrans<<<dim3(80,16), 256, 0, stream>>>(vpg, vpT);
  k_attn<<<dim3(32,16,NSPLIT), 256, 0, stream>>>(q_b, kpg, vpT, oP, ml);
  k_mlw<<<256, 256, 0, stream>>>(ml, comb);
  k_gemm2<1><<<dim3(64,4), 256, 0, stream>>>(nullptr, woutT, b_out, nullptr, nullptr, nullptr, outp, oP, comb);
}